// Round 5
// baseline (335.926 us; speedup 1.0000x reference)
//
#include <hip/hip_runtime.h>
#include <hip/hip_bf16.h>

typedef unsigned short u16;
typedef unsigned int u32;
typedef __attribute__((ext_vector_type(8))) __bf16 bf16x8;
typedef __attribute__((ext_vector_type(4))) float f32x4;

#define INV_HD  0.03125f
#define INV_SHD 0.17677669529663687f
#define LOG2E   1.4426950408889634f

__device__ __forceinline__ float b2f(u16 u) {
  union { u32 i; float f; } v; v.i = ((u32)u) << 16; return v.f;
}
__device__ __forceinline__ u16 f2b(float f) {
  union { float f; u32 i; } v; v.f = f;
  u32 x = v.i;
  return (u16)((x + 0x7fffu + ((x >> 16) & 1u)) >> 16);
}
__device__ __forceinline__ bf16x8 ld16(const u16* p) {
  return *reinterpret_cast<const bf16x8*>(p);
}
union U8 { bf16x8 v; u16 s[8]; };
__device__ __forceinline__ bf16x8 cvt8(const float* p) {
  U8 u;
#pragma unroll
  for (int j = 0; j < 8; ++j) u.s[j] = f2b(p[j]);
  return u.v;
}
__device__ __forceinline__ u32 cvtpk(float a, float b) {
  u32 r;
  asm("v_cvt_pk_bf16_f32 %0, %1, %2" : "=v"(r) : "v"(a), "v"(b));
  return r;
}

// ---------------- weight transpose + f32->bf16: WT[n][k] = W[k][n], K = 256 ----------------
__global__ void kT(const float* __restrict__ W, u16* __restrict__ WT, int N, int total)
{
  int i = blockIdx.x * 256 + threadIdx.x;
  if (i >= total) return;
  int n = i >> 8, k = i & 255;
  WT[i] = f2b(W[(size_t)k * N + n]);
}

// ---------------- pre-expand rel-pos bias into MFMA C-layout (swapped kSelf) ----------------
// BiasC[h][qt][kt][lane][i] bf16, pre-scaled by INV_SHD*LOG2E.  8192 threads.
__global__ void kBias(const float* __restrict__ tblg, u16* __restrict__ BiasC)
{
  int gid = blockIdx.x * 256 + threadIdx.x;
  int lane = gid & 63, t = gid >> 6;     // t = h*16 + qt*4 + kt, in [0,128)
  int h = t >> 4, qt = (t >> 2) & 3, kt = t & 3;
  int lr = lane & 15, kg = lane >> 4;
  int q = qt * 16 + lr;
  int qi = q >> 3, qj = q & 7;
  ushort4 out;
#pragma unroll
  for (int i = 0; i < 4; ++i) {
    int key = kt * 16 + kg * 4 + i;
    int ki = key >> 3, kj = key & 7;
    int idx = (qi - ki + 7) * 15 + (qj - kj + 7);
    ((u16*)&out)[i] = f2b(tblg[idx * 8 + h] * (INV_SHD * LOG2E));
  }
  *reinterpret_cast<ushort4*>(BiasC + (size_t)(t * 64 + lane) * 4) = out;
}

// ---------------- QKV GEMM: [49152,256](f32) @ [256,768]
__global__ __launch_bounds__(256) void kQKV(
    const float* __restrict__ xs1, const float* __restrict__ xs2, const float* __restrict__ xq,
    const u16* __restrict__ WT, const float* __restrict__ bias,
    u16* __restrict__ qk, u16* __restrict__ VT, u16* __restrict__ VST)
{
  __shared__ u16 vt[128 * 17];
  const int tid = threadIdx.x;
  const int lane = tid & 63, wid = tid >> 6;
  const int lr = lane & 15, kg = lane >> 4;
  const int m0 = blockIdx.x * 128 + wid * 32;
  const int n0 = blockIdx.y * 384;
  const int m0blk = blockIdx.x * 128;
  const int bb = m0blk / 6144, rloc = m0blk - bb * 6144;

  bf16x8 a[2][8];
#pragma unroll
  for (int mt = 0; mt < 2; ++mt) {
    int row = m0 + mt * 16 + lr;
    int b = row / 6144, r = row - b * 6144;
    const float* src;
    if (r < 4096)      src = xs1 + ((size_t)b * 4096 + r) * 256;
    else if (r < 5120) src = xs2 + ((size_t)b * 1024 + (r - 4096)) * 256;
    else               src = xq  + ((size_t)b * 1024 + (r - 5120)) * 256;
    src += kg * 8;
#pragma unroll
    for (int ks = 0; ks < 8; ++ks) a[mt][ks] = cvt8(src + ks * 32);
  }

  for (int nt = 0; nt < 24; ++nt) {
    const int n = n0 + nt * 16;
    const u16* bp = WT + (size_t)(n + lr) * 256 + kg * 8;
    f32x4 acc0 = {0.f,0.f,0.f,0.f}, acc1 = {0.f,0.f,0.f,0.f};
#pragma unroll
    for (int ks = 0; ks < 8; ++ks) {
      bf16x8 bq = ld16(bp + ks * 32);
      acc0 = __builtin_amdgcn_mfma_f32_16x16x32_bf16(a[0][ks], bq, acc0, 0, 0, 0);
      acc1 = __builtin_amdgcn_mfma_f32_16x16x32_bf16(a[1][ks], bq, acc1, 0, 0, 0);
    }
    float bv = bias[n + lr];
    if (n < 512) {
#pragma unroll
      for (int i = 0; i < 4; ++i) {
        int r0 = m0 + kg * 4 + i;
        qk[(size_t)r0 * 512 + n + lr]        = f2b(acc0[i] + bv);
        qk[(size_t)(r0 + 16) * 512 + n + lr] = f2b(acc1[i] + bv);
      }
    } else {
      const int mloc = wid * 32 + kg * 4;
#pragma unroll
      for (int i = 0; i < 4; ++i) {
        vt[(mloc + i) * 17 + lr]      = f2b(acc0[i] + bv);
        vt[(mloc + 16 + i) * 17 + lr] = f2b(acc1[i] + bv);
      }
      __syncthreads();
      {
        const int c = tid >> 4, kchunk = tid & 15;
        const int nc = n + c;
        const int hh = (nc - 512) >> 5, dd = (nc - 512) & 31;
        U8 pk;
#pragma unroll
        for (int j = 0; j < 8; ++j) pk.s[j] = vt[(kchunk * 8 + j) * 17 + c];
        u16* dst;
        if (rloc < 4096) {
          int y = (rloc >> 6) + (kchunk >> 3);
          int wkey = ((y >> 3) * 8 + (kchunk & 7)) * 64 + (y & 7) * 8;
          dst = VST + ((size_t)(bb * 8 + hh) * 32 + dd) * 4096 + wkey;
        } else {
          int key0 = (rloc < 5120) ? (rloc - 4096 + kchunk * 8)
                                   : (1024 + rloc - 5120 + kchunk * 8);
          dst = VT + ((size_t)(bb * 8 + hh) * 32 + dd) * 2048 + key0;
        }
        *reinterpret_cast<bf16x8*>(dst) = pk.v;
      }
      __syncthreads();
    }
  }
}

// ---------------- windowed self-attention, swapped QK^T (lane owns a q-row) ----------------
__global__ __launch_bounds__(256) void kSelf(
    const u16* __restrict__ qk, const u16* __restrict__ BiasC,
    const u16* __restrict__ VST, u16* __restrict__ X)
{
  __shared__ u16 Pl[4][64 * 72];
  const int tid = threadIdx.x;
  const int lane = tid & 63, wid = tid >> 6;
  const int lr = lane & 15, kg = lane >> 4;
  const int w = blockIdx.x >> 1;
  const int h = (blockIdx.x & 1) * 4 + wid;
  const int b = w >> 6, wz = w & 63;
  const int wy = wz >> 3, wx = wz & 7;
  const size_t tokbase = (size_t)b * 6144 + wy * 512 + wx * 8;
  const size_t xbase   = (size_t)b * 5120 + wy * 512 + wx * 8;
  u16* P = Pl[wid];

  bf16x8 qf[4], kf[4];
#pragma unroll
  for (int t4 = 0; t4 < 4; ++t4) {
    int t = t4 * 16 + lr;
    size_t row = tokbase + (t >> 3) * 64 + (t & 7);
    const u16* p = qk + row * 512 + h * 32 + kg * 8;
    qf[t4] = ld16(p);
    kf[t4] = ld16(p + 256);
  }
  bf16x8 vf[2][2];
#pragma unroll
  for (int dt = 0; dt < 2; ++dt)
#pragma unroll
    for (int ks = 0; ks < 2; ++ks)
      vf[dt][ks] = ld16(VST + ((size_t)(b * 8 + h) * 32 + dt * 16 + lr) * 4096
                        + wz * 64 + ks * 32 + kg * 8);
  // swapped QK^T: st[qt][kt] lane(kg,lr) holds q=qt*16+lr, key=kt*16+kg*4+i
  f32x4 st[4][4];
#pragma unroll
  for (int qt = 0; qt < 4; ++qt)
#pragma unroll
    for (int kt = 0; kt < 4; ++kt) {
      f32x4 z = {0.f,0.f,0.f,0.f};
      st[qt][kt] = __builtin_amdgcn_mfma_f32_16x16x32_bf16(kf[kt], qf[qt], z, 0, 0, 0);
    }
  // bias add (pre-expanded, pre-scaled) + score scale
  const float c0 = INV_HD * LOG2E;
#pragma unroll
  for (int qt = 0; qt < 4; ++qt)
#pragma unroll
    for (int kt = 0; kt < 4; ++kt) {
      ushort4 bv = *reinterpret_cast<const ushort4*>(
          BiasC + (size_t)((h * 16 + qt * 4 + kt) * 64 + lane) * 4);
      st[qt][kt][0] = st[qt][kt][0] * c0 + b2f(bv.x);
      st[qt][kt][1] = st[qt][kt][1] * c0 + b2f(bv.y);
      st[qt][kt][2] = st[qt][kt][2] * c0 + b2f(bv.z);
      st[qt][kt][3] = st[qt][kt][3] * c0 + b2f(bv.w);
    }
  // per-q-row softmax: 15 in-register fmax + 2 shfl, exp2, sum + 2 shfl
  float l[4];
#pragma unroll
  for (int qt = 0; qt < 4; ++qt) {
    float mx = -1e30f;
#pragma unroll
    for (int kt = 0; kt < 4; ++kt)
      mx = fmaxf(mx, fmaxf(fmaxf(st[qt][kt][0], st[qt][kt][1]),
                           fmaxf(st[qt][kt][2], st[qt][kt][3])));
    mx = fmaxf(mx, __shfl_xor(mx, 16, 64));
    mx = fmaxf(mx, __shfl_xor(mx, 32, 64));
    float lsum = 0.f;
#pragma unroll
    for (int kt = 0; kt < 4; ++kt)
#pragma unroll
      for (int i = 0; i < 4; ++i) {
        float p = exp2f(st[qt][kt][i] - mx);
        st[qt][kt][i] = p; lsum += p;
      }
    lsum += __shfl_xor(lsum, 16, 64);
    lsum += __shfl_xor(lsum, 32, 64);
    l[qt] = lsum;
  }
  // pack P (unnormalized) -> LDS
#pragma unroll
  for (int qt = 0; qt < 4; ++qt)
#pragma unroll
    for (int kt = 0; kt < 4; ++kt) {
      u32 w0 = cvtpk(st[qt][kt][0], st[qt][kt][1]);
      u32 w1 = cvtpk(st[qt][kt][2], st[qt][kt][3]);
      *reinterpret_cast<uint2*>(&P[(qt * 16 + lr) * 72 + kt * 16 + kg * 4]) = make_uint2(w0, w1);
    }
  // PV
  f32x4 o[4][2] = {};
#pragma unroll
  for (int qt = 0; qt < 4; ++qt)
#pragma unroll
    for (int ks = 0; ks < 2; ++ks) {
      bf16x8 pf = ld16(P + (qt * 16 + lr) * 72 + ks * 32 + kg * 8);
      o[qt][0] = __builtin_amdgcn_mfma_f32_16x16x32_bf16(pf, vf[0][ks], o[qt][0], 0, 0, 0);
      o[qt][1] = __builtin_amdgcn_mfma_f32_16x16x32_bf16(pf, vf[1][ks], o[qt][1], 0, 0, 0);
    }
  // epilogue: deferred normalization
#pragma unroll
  for (int qt = 0; qt < 4; ++qt)
#pragma unroll
    for (int i = 0; i < 4; ++i) {
      float li = __shfl(l[qt], kg * 4 + i, 16);
      float inv = 1.f / li;
      int t = qt * 16 + kg * 4 + i;
      size_t xrow = xbase + (t >> 3) * 64 + (t & 7);
#pragma unroll
      for (int dt = 0; dt < 2; ++dt)
        X[xrow * 256 + h * 32 + dt * 16 + lr] = f2b(o[qt][dt][i] * inv);
    }
}

// ---------------- cross attention, KV-split=2, partials to scratch ----------------
__global__ __launch_bounds__(256, 6) void kCross(
    const u16* __restrict__ qk, const u16* __restrict__ VT,
    u16* __restrict__ Opart, float* __restrict__ ML)
{
  __shared__ u16 Pl[4][16 * 72];
  const int tid = threadIdx.x;
  const int lane = tid & 63, wid = tid >> 6;
  const int lr = lane & 15, kg = lane >> 4;
  const int bh = blockIdx.x, b = bh >> 3, h = bh & 7;
  const int q0 = blockIdx.y * 64 + wid * 16;
  const int s = blockIdx.z;
  const size_t qrow0 = (size_t)b * 6144 + 5120;
  const size_t krow0 = (size_t)b * 6144 + 4096;
  const u16* kbase = qk + (s ? qrow0 : krow0) * 512;
  const u16* vtb = VT + (size_t)bh * 32 * 2048 + s * 1024;
  u16* P = Pl[wid];

  bf16x8 qf;
  {
    const float sc = INV_SHD * LOG2E;
    U8 u;
    u.v = ld16(qk + (qrow0 + q0 + lr) * 512 + h * 32 + kg * 8);
#pragma unroll
    for (int j = 0; j < 8; ++j) u.s[j] = f2b(b2f(u.s[j]) * sc);
    qf = u.v;
  }

  f32x4 o0 = {0.f,0.f,0.f,0.f}, o1 = {0.f,0.f,0.f,0.f};
  float m = -1e30f, l = 0.f;

#pragma unroll 1
  for (int ck = 0; ck < 16; ++ck) {
    const int kc0 = ck * 64;
    f32x4 st[4];
#pragma unroll
    for (int kt = 0; kt < 4; ++kt) {
      bf16x8 kf = ld16(kbase + (size_t)(kc0 + kt * 16 + lr) * 512 + 256 + h * 32 + kg * 8);
      f32x4 z = {0.f,0.f,0.f,0.f};
      st[kt] = __builtin_amdgcn_mfma_f32_16x16x32_bf16(kf, qf, z, 0, 0, 0);
    }
    bf16x8 vf0[2], vf1[2];
#pragma unroll
    for (int ks = 0; ks < 2; ++ks) {
      vf0[ks] = ld16(vtb + (size_t)lr * 2048 + kc0 + ks * 32 + kg * 8);
      vf1[ks] = ld16(vtb + (size_t)(16 + lr) * 2048 + kc0 + ks * 32 + kg * 8);
    }
    float mx = fmaxf(fmaxf(fmaxf(st[0][0], st[0][1]), fmaxf(st[0][2], st[0][3])),
                     fmaxf(fmaxf(st[1][0], st[1][1]), fmaxf(st[1][2], st[1][3])));
    mx = fmaxf(mx, fmaxf(fmaxf(fmaxf(st[2][0], st[2][1]), fmaxf(st[2][2], st[2][3])),
                         fmaxf(fmaxf(st[3][0], st[3][1]), fmaxf(st[3][2], st[3][3]))));
    mx = fmaxf(mx, __shfl_xor(mx, 16, 64));
    mx = fmaxf(mx, __shfl_xor(mx, 32, 64));
    if (__all(mx <= m + 8.f)) {
      // defer-max: keep m, no o-rescale
      float lsum = 0.f;
#pragma unroll
      for (int kt = 0; kt < 4; ++kt)
#pragma unroll
        for (int i = 0; i < 4; ++i) {
          float p = exp2f(st[kt][i] - m); st[kt][i] = p; lsum += p;
        }
      lsum += __shfl_xor(lsum, 16, 64);
      lsum += __shfl_xor(lsum, 32, 64);
      l += lsum;
    } else {
      float mn = fmaxf(m, mx);
      float sca = exp2f(m - mn);
      float lsum = 0.f;
#pragma unroll
      for (int kt = 0; kt < 4; ++kt)
#pragma unroll
        for (int i = 0; i < 4; ++i) {
          float p = exp2f(st[kt][i] - mn); st[kt][i] = p; lsum += p;
        }
      lsum += __shfl_xor(lsum, 16, 64);
      lsum += __shfl_xor(lsum, 32, 64);
      l = l * sca + lsum;
      m = mn;
#pragma unroll
      for (int i = 0; i < 4; ++i) {
        float si = __shfl(sca, kg * 4 + i, 16);
        o0[i] *= si; o1[i] *= si;
      }
    }
#pragma unroll
    for (int kt = 0; kt < 4; ++kt) {
      u32 w0 = cvtpk(st[kt][0], st[kt][1]);
      u32 w1 = cvtpk(st[kt][2], st[kt][3]);
      *reinterpret_cast<uint2*>(&P[lr * 72 + kt * 16 + kg * 4]) = make_uint2(w0, w1);
    }
#pragma unroll
    for (int ks = 0; ks < 2; ++ks) {
      bf16x8 pf = ld16(P + lr * 72 + ks * 32 + kg * 8);
      o0 = __builtin_amdgcn_mfma_f32_16x16x32_bf16(pf, vf0[ks], o0, 0, 0, 0);
      o1 = __builtin_amdgcn_mfma_f32_16x16x32_bf16(pf, vf1[ks], o1, 0, 0, 0);
    }
  }
  // write partials (unnormalized o + m,l)
  const size_t rowb = (size_t)(s * 64 + bh) * 1024;
#pragma unroll
  for (int i = 0; i < 4; ++i) {
    int q = q0 + kg * 4 + i;
    Opart[(rowb + q) * 32 + lr]      = f2b(o0[i]);
    Opart[(rowb + q) * 32 + 16 + lr] = f2b(o1[i]);
  }
  if (kg == 0) {
    float2 ml = make_float2(m, l);
    *reinterpret_cast<float2*>(ML + (rowb + q0 + lr) * 2) = ml;
  }
}

// ---------------- combine the 2 KV-splits ----------------
__global__ __launch_bounds__(256) void kComb(
    const u16* __restrict__ Opart, const float* __restrict__ ML, u16* __restrict__ X)
{
  int gid = blockIdx.x * 256 + threadIdx.x;   // 262144
  int row = gid >> 2;                         // bh*1024 + q
  int dp = (gid & 3) * 8;
  int bh = row >> 10, q = row & 1023;
  int b = bh >> 3, h = bh & 7;
  float2 ml0 = *reinterpret_cast<const float2*>(ML + (size_t)row * 2);
  float2 ml1 = *reinterpret_cast<const float2*>(ML + (size_t)(65536 + row) * 2);
  float ms = fmaxf(ml0.x, ml1.x);
  float f0 = exp2f(ml0.x - ms), f1 = exp2f(ml1.x - ms);
  float inv = 1.f / (ml0.y * f0 + ml1.y * f1);
  f0 *= inv; f1 *= inv;
  U8 a, c, r;
  a.v = ld16(Opart + (size_t)row * 32 + dp);
  c.v = ld16(Opart + ((size_t)(65536 + row) * 32 + dp));
#pragma unroll
  for (int j = 0; j < 8; ++j) r.s[j] = f2b(b2f(a.s[j]) * f0 + b2f(c.s[j]) * f1);
  size_t xrow = (size_t)b * 5120 + 4096 + q;
  *reinterpret_cast<bf16x8*>(X + xrow * 256 + h * 32 + dp) = r.v;
}

// ---------------- output projection: [40960,256] @ [256,256] -> f32 out ----------------
__global__ __launch_bounds__(256) void kProj(
    const u16* __restrict__ Xin, const u16* __restrict__ WT, const float* __restrict__ bias,
    float* __restrict__ out)
{
  const int tid = threadIdx.x;
  const int lane = tid & 63, wid = tid >> 6;
  const int lr = lane & 15, kg = lane >> 4;
  const int m0 = blockIdx.x * 128 + wid * 32;
  const int n0 = blockIdx.y * 128;
  bf16x8 a[2][8];
#pragma unroll
  for (int mt = 0; mt < 2; ++mt) {
    const u16* src = Xin + (size_t)(m0 + mt * 16 + lr) * 256 + kg * 8;
#pragma unroll
    for (int ks = 0; ks < 8; ++ks) a[mt][ks] = ld16(src + ks * 32);
  }
  for (int nt = 0; nt < 8; ++nt) {
    const int n = n0 + nt * 16;
    const u16* bp = WT + (size_t)(n + lr) * 256 + kg * 8;
    f32x4 acc0 = {0.f,0.f,0.f,0.f}, acc1 = {0.f,0.f,0.f,0.f};
#pragma unroll
    for (int ks = 0; ks < 8; ++ks) {
      bf16x8 bq = ld16(bp + ks * 32);
      acc0 = __builtin_amdgcn_mfma_f32_16x16x32_bf16(a[0][ks], bq, acc0, 0, 0, 0);
      acc1 = __builtin_amdgcn_mfma_f32_16x16x32_bf16(a[1][ks], bq, acc1, 0, 0, 0);
    }
    float bv = bias[n + lr];
#pragma unroll
    for (int i = 0; i < 4; ++i) {
      int r0 = m0 + kg * 4 + i;
      out[(size_t)r0 * 256 + n + lr]        = acc0[i] + bv;
      out[(size_t)(r0 + 16) * 256 + n + lr] = acc1[i] + bv;
    }
  }
}

extern "C" void kernel_launch(void* const* d_in, const int* in_sizes, int n_in,
                              void* d_out, int out_size, void* d_ws, size_t ws_size,
                              hipStream_t stream)
{
  const float* xs1   = (const float*)d_in[0];
  const float* xs2   = (const float*)d_in[1];
  const float* xq    = (const float*)d_in[2];
  const float* Wqkv  = (const float*)d_in[3];
  const float* bqkv  = (const float*)d_in[4];
  const float* Wproj = (const float*)d_in[5];
  const float* bproj = (const float*)d_in[6];
  const float* tbl   = (const float*)d_in[7];

  u16* ws  = (u16*)d_ws;
  u16* qk  = ws;                 // 49152*512 = 25165824 elems (bf16)
  u16* X   = qk + 25165824;      // 40960*256 = 10485760
  u16* WTq = X + 10485760;       // 768*256   =   196608
  u16* WTp = WTq + 196608;       // 256*256   =    65536
  u16* VT  = WTp + 65536;        // 8*8*32*2048 = 4194304
  u16* VST = VT + 4194304;       // 8*8*32*4096 = 8388608

  // scratch inside d_out (fully overwritten by kProj at the end):
  u16*   BiasC = (u16*)d_out;                               // 131072 u16  (256 KB)
  float* ML    = (float*)((char*)d_out + 262144);           // 262144 f32  (1 MB)
  u16*   Opart = (u16*)((char*)d_out + 1310720);            // 4194304 u16 (8 MB)

  kT<<<768, 256, 0, stream>>>(Wqkv, WTq, 768, 196608);
  kT<<<256, 256, 0, stream>>>(Wproj, WTp, 256, 65536);
  kBias<<<32, 256, 0, stream>>>(tbl, BiasC);
  kQKV<<<dim3(384, 2), 256, 0, stream>>>(xs1, xs2, xq, WTq, bqkv, qk, VT, VST);
  kSelf<<<1024, 256, 0, stream>>>(qk, BiasC, VST, X);
  kCross<<<dim3(64, 16, 2), 256, 0, stream>>>(qk, VT, Opart, ML);
  kComb<<<1024, 256, 0, stream>>>(Opart, ML, X);
  kProj<<<dim3(320, 2), 256, 0, stream>>>(X, WTp, bproj, (float*)d_out);
}

// Round 6
// 298.206 us; speedup vs baseline: 1.1265x; 1.1265x over previous
//
#include <hip/hip_runtime.h>
#include <hip/hip_bf16.h>

typedef unsigned short u16;
typedef unsigned int u32;
typedef __attribute__((ext_vector_type(8))) __bf16 bf16x8;
typedef __attribute__((ext_vector_type(4))) float f32x4;

#define INV_HD  0.03125f
#define INV_SHD 0.17677669529663687f
#define LOG2E   1.4426950408889634f

__device__ __forceinline__ float b2f(u16 u) {
  union { u32 i; float f; } v; v.i = ((u32)u) << 16; return v.f;
}
__device__ __forceinline__ u16 f2b(float f) {
  union { float f; u32 i; } v; v.f = f;
  u32 x = v.i;
  return (u16)((x + 0x7fffu + ((x >> 16) & 1u)) >> 16);
}
__device__ __forceinline__ bf16x8 ld16(const u16* p) {
  return *reinterpret_cast<const bf16x8*>(p);
}
union U8 { bf16x8 v; u16 s[8]; };
__device__ __forceinline__ bf16x8 cvt8(const float* p) {
  U8 u;
#pragma unroll
  for (int j = 0; j < 8; ++j) u.s[j] = f2b(p[j]);
  return u.v;
}
__device__ __forceinline__ u32 cvtpk(float a, float b) {
  u32 r;
  asm("v_cvt_pk_bf16_f32 %0, %1, %2" : "=v"(r) : "v"(a), "v"(b));
  return r;
}

// ---------------- weight transpose + f32->bf16: WT[n][k] = W[k][n], K = 256 ----------------
__global__ void kT(const float* __restrict__ W, u16* __restrict__ WT, int N, int total)
{
  int i = blockIdx.x * 256 + threadIdx.x;
  if (i >= total) return;
  int n = i >> 8, k = i & 255;
  WT[i] = f2b(W[(size_t)k * N + n]);
}

// ---------------- pre-expand rel-pos bias into MFMA C-layout (swapped kSelf) ----------------
__global__ void kBias(const float* __restrict__ tblg, u16* __restrict__ BiasC)
{
  int gid = blockIdx.x * 256 + threadIdx.x;
  int lane = gid & 63, t = gid >> 6;     // t = h*16 + qt*4 + kt, in [0,128)
  int h = t >> 4, qt = (t >> 2) & 3, kt = t & 3;
  int lr = lane & 15, kg = lane >> 4;
  int q = qt * 16 + lr;
  int qi = q >> 3, qj = q & 7;
  ushort4 out;
#pragma unroll
  for (int i = 0; i < 4; ++i) {
    int key = kt * 16 + kg * 4 + i;
    int ki = key >> 3, kj = key & 7;
    int idx = (qi - ki + 7) * 15 + (qj - kj + 7);
    ((u16*)&out)[i] = f2b(tblg[idx * 8 + h] * (INV_SHD * LOG2E));
  }
  *reinterpret_cast<ushort4*>(BiasC + (size_t)(t * 64 + lane) * 4) = out;
}

// ---------------- QKV GEMM: [49152,256](f32) @ [256,768]
__global__ __launch_bounds__(256) void kQKV(
    const float* __restrict__ xs1, const float* __restrict__ xs2, const float* __restrict__ xq,
    const u16* __restrict__ WT, const float* __restrict__ bias,
    u16* __restrict__ qk, u16* __restrict__ VT, u16* __restrict__ VST)
{
  __shared__ u16 vt[128 * 17];
  const int tid = threadIdx.x;
  const int lane = tid & 63, wid = tid >> 6;
  const int lr = lane & 15, kg = lane >> 4;
  const int m0 = blockIdx.x * 128 + wid * 32;
  const int n0 = blockIdx.y * 384;
  const int m0blk = blockIdx.x * 128;
  const int bb = m0blk / 6144, rloc = m0blk - bb * 6144;

  bf16x8 a[2][8];
#pragma unroll
  for (int mt = 0; mt < 2; ++mt) {
    int row = m0 + mt * 16 + lr;
    int b = row / 6144, r = row - b * 6144;
    const float* src;
    if (r < 4096)      src = xs1 + ((size_t)b * 4096 + r) * 256;
    else if (r < 5120) src = xs2 + ((size_t)b * 1024 + (r - 4096)) * 256;
    else               src = xq  + ((size_t)b * 1024 + (r - 5120)) * 256;
    src += kg * 8;
#pragma unroll
    for (int ks = 0; ks < 8; ++ks) a[mt][ks] = cvt8(src + ks * 32);
  }

  for (int nt = 0; nt < 24; ++nt) {
    const int n = n0 + nt * 16;
    const u16* bp = WT + (size_t)(n + lr) * 256 + kg * 8;
    f32x4 acc0 = {0.f,0.f,0.f,0.f}, acc1 = {0.f,0.f,0.f,0.f};
#pragma unroll
    for (int ks = 0; ks < 8; ++ks) {
      bf16x8 bq = ld16(bp + ks * 32);
      acc0 = __builtin_amdgcn_mfma_f32_16x16x32_bf16(a[0][ks], bq, acc0, 0, 0, 0);
      acc1 = __builtin_amdgcn_mfma_f32_16x16x32_bf16(a[1][ks], bq, acc1, 0, 0, 0);
    }
    float bv = bias[n + lr];
    if (n < 512) {
#pragma unroll
      for (int i = 0; i < 4; ++i) {
        int r0 = m0 + kg * 4 + i;
        qk[(size_t)r0 * 512 + n + lr]        = f2b(acc0[i] + bv);
        qk[(size_t)(r0 + 16) * 512 + n + lr] = f2b(acc1[i] + bv);
      }
    } else {
      const int mloc = wid * 32 + kg * 4;
#pragma unroll
      for (int i = 0; i < 4; ++i) {
        vt[(mloc + i) * 17 + lr]      = f2b(acc0[i] + bv);
        vt[(mloc + 16 + i) * 17 + lr] = f2b(acc1[i] + bv);
      }
      __syncthreads();
      {
        const int c = tid >> 4, kchunk = tid & 15;
        const int nc = n + c;
        const int hh = (nc - 512) >> 5, dd = (nc - 512) & 31;
        U8 pk;
#pragma unroll
        for (int j = 0; j < 8; ++j) pk.s[j] = vt[(kchunk * 8 + j) * 17 + c];
        u16* dst;
        if (rloc < 4096) {
          int y = (rloc >> 6) + (kchunk >> 3);
          int wkey = ((y >> 3) * 8 + (kchunk & 7)) * 64 + (y & 7) * 8;
          dst = VST + ((size_t)(bb * 8 + hh) * 32 + dd) * 4096 + wkey;
        } else {
          int key0 = (rloc < 5120) ? (rloc - 4096 + kchunk * 8)
                                   : (1024 + rloc - 5120 + kchunk * 8);
          dst = VT + ((size_t)(bb * 8 + hh) * 32 + dd) * 2048 + key0;
        }
        *reinterpret_cast<bf16x8*>(dst) = pk.v;
      }
      __syncthreads();
    }
  }
}

// ---------------- windowed self-attention, swapped QK^T (lane owns a q-row) ----------------
__global__ __launch_bounds__(256) void kSelf(
    const u16* __restrict__ qk, const u16* __restrict__ BiasC,
    const u16* __restrict__ VST, u16* __restrict__ X)
{
  __shared__ u16 Pl[4][64 * 72];
  const int tid = threadIdx.x;
  const int lane = tid & 63, wid = tid >> 6;
  const int lr = lane & 15, kg = lane >> 4;
  const int w = blockIdx.x >> 1;
  const int h = (blockIdx.x & 1) * 4 + wid;
  const int b = w >> 6, wz = w & 63;
  const int wy = wz >> 3, wx = wz & 7;
  const size_t tokbase = (size_t)b * 6144 + wy * 512 + wx * 8;
  const size_t xbase   = (size_t)b * 5120 + wy * 512 + wx * 8;
  u16* P = Pl[wid];

  bf16x8 qf[4], kf[4];
#pragma unroll
  for (int t4 = 0; t4 < 4; ++t4) {
    int t = t4 * 16 + lr;
    size_t row = tokbase + (t >> 3) * 64 + (t & 7);
    const u16* p = qk + row * 512 + h * 32 + kg * 8;
    qf[t4] = ld16(p);
    kf[t4] = ld16(p + 256);
  }
  bf16x8 vf[2][2];
#pragma unroll
  for (int dt = 0; dt < 2; ++dt)
#pragma unroll
    for (int ks = 0; ks < 2; ++ks)
      vf[dt][ks] = ld16(VST + ((size_t)(b * 8 + h) * 32 + dt * 16 + lr) * 4096
                        + wz * 64 + ks * 32 + kg * 8);
  f32x4 st[4][4];
#pragma unroll
  for (int qt = 0; qt < 4; ++qt)
#pragma unroll
    for (int kt = 0; kt < 4; ++kt) {
      f32x4 z = {0.f,0.f,0.f,0.f};
      st[qt][kt] = __builtin_amdgcn_mfma_f32_16x16x32_bf16(kf[kt], qf[qt], z, 0, 0, 0);
    }
  const float c0 = INV_HD * LOG2E;
#pragma unroll
  for (int qt = 0; qt < 4; ++qt)
#pragma unroll
    for (int kt = 0; kt < 4; ++kt) {
      ushort4 bv = *reinterpret_cast<const ushort4*>(
          BiasC + (size_t)((h * 16 + qt * 4 + kt) * 64 + lane) * 4);
      st[qt][kt][0] = st[qt][kt][0] * c0 + b2f(bv.x);
      st[qt][kt][1] = st[qt][kt][1] * c0 + b2f(bv.y);
      st[qt][kt][2] = st[qt][kt][2] * c0 + b2f(bv.z);
      st[qt][kt][3] = st[qt][kt][3] * c0 + b2f(bv.w);
    }
  float l[4];
#pragma unroll
  for (int qt = 0; qt < 4; ++qt) {
    float mx = -1e30f;
#pragma unroll
    for (int kt = 0; kt < 4; ++kt)
      mx = fmaxf(mx, fmaxf(fmaxf(st[qt][kt][0], st[qt][kt][1]),
                           fmaxf(st[qt][kt][2], st[qt][kt][3])));
    mx = fmaxf(mx, __shfl_xor(mx, 16, 64));
    mx = fmaxf(mx, __shfl_xor(mx, 32, 64));
    float lsum = 0.f;
#pragma unroll
    for (int kt = 0; kt < 4; ++kt)
#pragma unroll
      for (int i = 0; i < 4; ++i) {
        float p = exp2f(st[qt][kt][i] - mx);
        st[qt][kt][i] = p; lsum += p;
      }
    lsum += __shfl_xor(lsum, 16, 64);
    lsum += __shfl_xor(lsum, 32, 64);
    l[qt] = lsum;
  }
#pragma unroll
  for (int qt = 0; qt < 4; ++qt)
#pragma unroll
    for (int kt = 0; kt < 4; ++kt) {
      u32 w0 = cvtpk(st[qt][kt][0], st[qt][kt][1]);
      u32 w1 = cvtpk(st[qt][kt][2], st[qt][kt][3]);
      *reinterpret_cast<uint2*>(&P[(qt * 16 + lr) * 72 + kt * 16 + kg * 4]) = make_uint2(w0, w1);
    }
  f32x4 o[4][2] = {};
#pragma unroll
  for (int qt = 0; qt < 4; ++qt)
#pragma unroll
    for (int ks = 0; ks < 2; ++ks) {
      bf16x8 pf = ld16(P + (qt * 16 + lr) * 72 + ks * 32 + kg * 8);
      o[qt][0] = __builtin_amdgcn_mfma_f32_16x16x32_bf16(pf, vf[0][ks], o[qt][0], 0, 0, 0);
      o[qt][1] = __builtin_amdgcn_mfma_f32_16x16x32_bf16(pf, vf[1][ks], o[qt][1], 0, 0, 0);
    }
#pragma unroll
  for (int qt = 0; qt < 4; ++qt)
#pragma unroll
    for (int i = 0; i < 4; ++i) {
      float li = __shfl(l[qt], kg * 4 + i, 16);
      float inv = 1.f / li;
      int t = qt * 16 + kg * 4 + i;
      size_t xrow = xbase + (t >> 3) * 64 + (t & 7);
#pragma unroll
      for (int dt = 0; dt < 2; ++dt)
        X[xrow * 256 + h * 32 + dt * 16 + lr] = f2b(o[qt][dt][i] * inv);
    }
}

// ---------------- cross attention helpers: load 64-key tile / process 64-key tile ----------------
__device__ __forceinline__ void cload(
    const u16* __restrict__ kbase, const u16* __restrict__ vbase, int kc0, int lr, int kg,
    bf16x8 (&kf)[4], bf16x8 (&vf)[4])
{
#pragma unroll
  for (int kt = 0; kt < 4; ++kt)
    kf[kt] = ld16(kbase + (size_t)(kc0 + kt * 16 + lr) * 512);
#pragma unroll
  for (int ks = 0; ks < 2; ++ks) {
    vf[ks]     = ld16(vbase + (size_t)lr * 2048 + kc0 + ks * 32 + kg * 8);
    vf[2 + ks] = ld16(vbase + (size_t)(16 + lr) * 2048 + kc0 + ks * 32 + kg * 8);
  }
}

__device__ __forceinline__ void cstep(
    const bf16x8 (&kf)[4], const bf16x8 (&vf)[4], bf16x8 qf,
    u16* P, int lr, int kg, f32x4& o0, f32x4& o1, float& m, float& l)
{
  f32x4 st[4];
#pragma unroll
  for (int kt = 0; kt < 4; ++kt) {
    f32x4 z = {0.f,0.f,0.f,0.f};
    st[kt] = __builtin_amdgcn_mfma_f32_16x16x32_bf16(kf[kt], qf, z, 0, 0, 0);
  }
  float mx = fmaxf(fmaxf(fmaxf(st[0][0], st[0][1]), fmaxf(st[0][2], st[0][3])),
                   fmaxf(fmaxf(st[1][0], st[1][1]), fmaxf(st[1][2], st[1][3])));
  mx = fmaxf(mx, fmaxf(fmaxf(fmaxf(st[2][0], st[2][1]), fmaxf(st[2][2], st[2][3])),
                       fmaxf(fmaxf(st[3][0], st[3][1]), fmaxf(st[3][2], st[3][3]))));
  mx = fmaxf(mx, __shfl_xor(mx, 16, 64));
  mx = fmaxf(mx, __shfl_xor(mx, 32, 64));
  if (__all(mx <= m + 8.f)) {
    float lsum = 0.f;
#pragma unroll
    for (int kt = 0; kt < 4; ++kt)
#pragma unroll
      for (int i = 0; i < 4; ++i) {
        float p = exp2f(st[kt][i] - m); st[kt][i] = p; lsum += p;
      }
    lsum += __shfl_xor(lsum, 16, 64);
    lsum += __shfl_xor(lsum, 32, 64);
    l += lsum;
  } else {
    float mn = fmaxf(m, mx);
    float sca = exp2f(m - mn);
    float lsum = 0.f;
#pragma unroll
    for (int kt = 0; kt < 4; ++kt)
#pragma unroll
      for (int i = 0; i < 4; ++i) {
        float p = exp2f(st[kt][i] - mn); st[kt][i] = p; lsum += p;
      }
    lsum += __shfl_xor(lsum, 16, 64);
    lsum += __shfl_xor(lsum, 32, 64);
    l = l * sca + lsum;
    m = mn;
#pragma unroll
    for (int i = 0; i < 4; ++i) {
      float si = __shfl(sca, kg * 4 + i, 16);
      o0[i] *= si; o1[i] *= si;
    }
  }
#pragma unroll
  for (int kt = 0; kt < 4; ++kt) {
    u32 w0 = cvtpk(st[kt][0], st[kt][1]);
    u32 w1 = cvtpk(st[kt][2], st[kt][3]);
    *reinterpret_cast<uint2*>(&P[lr * 72 + kt * 16 + kg * 4]) = make_uint2(w0, w1);
  }
#pragma unroll
  for (int ks = 0; ks < 2; ++ks) {
    bf16x8 pf = ld16(P + lr * 72 + ks * 32 + kg * 8);
    o0 = __builtin_amdgcn_mfma_f32_16x16x32_bf16(pf, vf[ks],     o0, 0, 0, 0);
    o1 = __builtin_amdgcn_mfma_f32_16x16x32_bf16(pf, vf[2 + ks], o1, 0, 0, 0);
  }
}

// ---------------- cross attention, KV-split=2, double-buffered K/V prefetch ----------------
__global__ __launch_bounds__(256, 4) void kCross(
    const u16* __restrict__ qk, const u16* __restrict__ VT,
    u16* __restrict__ Opart, float* __restrict__ ML)
{
  __shared__ u16 Pl[4][16 * 72];
  const int tid = threadIdx.x;
  const int lane = tid & 63, wid = tid >> 6;
  const int lr = lane & 15, kg = lane >> 4;
  const int bh = blockIdx.x, b = bh >> 3, h = bh & 7;
  const int q0 = blockIdx.y * 64 + wid * 16;
  const int s = blockIdx.z;
  const size_t qrow0 = (size_t)b * 6144 + 5120;
  const size_t krow0 = (size_t)b * 6144 + 4096;
  const u16* kbase = qk + ((s ? qrow0 : krow0) * 512) + 256 + h * 32 + kg * 8;
  const u16* vbase = VT + (size_t)bh * 32 * 2048 + s * 1024;
  u16* P = Pl[wid];

  bf16x8 qf;
  {
    const float sc = INV_SHD * LOG2E;
    U8 u;
    u.v = ld16(qk + (qrow0 + q0 + lr) * 512 + h * 32 + kg * 8);
#pragma unroll
    for (int j = 0; j < 8; ++j) u.s[j] = f2b(b2f(u.s[j]) * sc);
    qf = u.v;
  }

  f32x4 o0 = {0.f,0.f,0.f,0.f}, o1 = {0.f,0.f,0.f,0.f};
  float m = -1e30f, l = 0.f;

  bf16x8 kA[4], vA[4], kB[4], vB[4];
  cload(kbase, vbase, 0, lr, kg, kA, vA);
#pragma unroll 1
  for (int ck2 = 0; ck2 < 8; ++ck2) {
    const int kc = ck2 * 128;
    cload(kbase, vbase, (kc + 64) & 1023, lr, kg, kB, vB);   // prefetch next tile
    cstep(kA, vA, qf, P, lr, kg, o0, o1, m, l);              // compute current
    cload(kbase, vbase, (kc + 128) & 1023, lr, kg, kA, vA);
    cstep(kB, vB, qf, P, lr, kg, o0, o1, m, l);
  }

  const size_t rowb = (size_t)(s * 64 + bh) * 1024;
#pragma unroll
  for (int i = 0; i < 4; ++i) {
    int q = q0 + kg * 4 + i;
    Opart[(rowb + q) * 32 + lr]      = f2b(o0[i]);
    Opart[(rowb + q) * 32 + 16 + lr] = f2b(o1[i]);
  }
  if (kg == 0) {
    float2 ml = make_float2(m, l);
    *reinterpret_cast<float2*>(ML + (rowb + q0 + lr) * 2) = ml;
  }
}

// ---------------- combine the 2 KV-splits ----------------
__global__ __launch_bounds__(256) void kComb(
    const u16* __restrict__ Opart, const float* __restrict__ ML, u16* __restrict__ X)
{
  int gid = blockIdx.x * 256 + threadIdx.x;   // 262144
  int row = gid >> 2;                         // bh*1024 + q
  int dp = (gid & 3) * 8;
  int bh = row >> 10, q = row & 1023;
  int b = bh >> 3, h = bh & 7;
  float2 ml0 = *reinterpret_cast<const float2*>(ML + (size_t)row * 2);
  float2 ml1 = *reinterpret_cast<const float2*>(ML + (size_t)(65536 + row) * 2);
  float ms = fmaxf(ml0.x, ml1.x);
  float f0 = exp2f(ml0.x - ms), f1 = exp2f(ml1.x - ms);
  float inv = 1.f / (ml0.y * f0 + ml1.y * f1);
  f0 *= inv; f1 *= inv;
  U8 a, c, r;
  a.v = ld16(Opart + (size_t)row * 32 + dp);
  c.v = ld16(Opart + ((size_t)(65536 + row) * 32 + dp));
#pragma unroll
  for (int j = 0; j < 8; ++j) r.s[j] = f2b(b2f(a.s[j]) * f0 + b2f(c.s[j]) * f1);
  size_t xrow = (size_t)b * 5120 + 4096 + q;
  *reinterpret_cast<bf16x8*>(X + xrow * 256 + h * 32 + dp) = r.v;
}

// ---------------- output projection: [40960,256] @ [256,256] -> f32 out ----------------
__global__ __launch_bounds__(256) void kProj(
    const u16* __restrict__ Xin, const u16* __restrict__ WT, const float* __restrict__ bias,
    float* __restrict__ out)
{
  const int tid = threadIdx.x;
  const int lane = tid & 63, wid = tid >> 6;
  const int lr = lane & 15, kg = lane >> 4;
  const int m0 = blockIdx.x * 128 + wid * 32;
  const int n0 = blockIdx.y * 128;
  bf16x8 a[2][8];
#pragma unroll
  for (int mt = 0; mt < 2; ++mt) {
    const u16* src = Xin + (size_t)(m0 + mt * 16 + lr) * 256 + kg * 8;
#pragma unroll
    for (int ks = 0; ks < 8; ++ks) a[mt][ks] = ld16(src + ks * 32);
  }
  for (int nt = 0; nt < 8; ++nt) {
    const int n = n0 + nt * 16;
    const u16* bp = WT + (size_t)(n + lr) * 256 + kg * 8;
    f32x4 acc0 = {0.f,0.f,0.f,0.f}, acc1 = {0.f,0.f,0.f,0.f};
#pragma unroll
    for (int ks = 0; ks < 8; ++ks) {
      bf16x8 bq = ld16(bp + ks * 32);
      acc0 = __builtin_amdgcn_mfma_f32_16x16x32_bf16(a[0][ks], bq, acc0, 0, 0, 0);
      acc1 = __builtin_amdgcn_mfma_f32_16x16x32_bf16(a[1][ks], bq, acc1, 0, 0, 0);
    }
    float bv = bias[n + lr];
#pragma unroll
    for (int i = 0; i < 4; ++i) {
      int r0 = m0 + kg * 4 + i;
      out[(size_t)r0 * 256 + n + lr]        = acc0[i] + bv;
      out[(size_t)(r0 + 16) * 256 + n + lr] = acc1[i] + bv;
    }
  }
}

extern "C" void kernel_launch(void* const* d_in, const int* in_sizes, int n_in,
                              void* d_out, int out_size, void* d_ws, size_t ws_size,
                              hipStream_t stream)
{
  const float* xs1   = (const float*)d_in[0];
  const float* xs2   = (const float*)d_in[1];
  const float* xq    = (const float*)d_in[2];
  const float* Wqkv  = (const float*)d_in[3];
  const float* bqkv  = (const float*)d_in[4];
  const float* Wproj = (const float*)d_in[5];
  const float* bproj = (const float*)d_in[6];
  const float* tbl   = (const float*)d_in[7];

  u16* ws  = (u16*)d_ws;
  u16* qk  = ws;                 // 49152*512 = 25165824 elems (bf16)
  u16* X   = qk + 25165824;      // 40960*256 = 10485760
  u16* WTq = X + 10485760;       // 768*256   =   196608
  u16* WTp = WTq + 196608;       // 256*256   =    65536
  u16* VT  = WTp + 65536;        // 8*8*32*2048 = 4194304
  u16* VST = VT + 4194304;       // 8*8*32*4096 = 8388608

  // scratch inside d_out (fully overwritten by kProj at the end):
  u16*   BiasC = (u16*)d_out;                               // 131072 u16  (256 KB)
  float* ML    = (float*)((char*)d_out + 262144);           // 262144 f32  (1 MB)
  u16*   Opart = (u16*)((char*)d_out + 1310720);            // 4194304 u16 (8 MB)

  kT<<<768, 256, 0, stream>>>(Wqkv, WTq, 768, 196608);
  kT<<<256, 256, 0, stream>>>(Wproj, WTp, 256, 65536);
  kBias<<<32, 256, 0, stream>>>(tbl, BiasC);
  kQKV<<<dim3(384, 2), 256, 0, stream>>>(xs1, xs2, xq, WTq, bqkv, qk, VT, VST);
  kSelf<<<1024, 256, 0, stream>>>(qk, BiasC, VST, X);
  kCross<<<dim3(64, 16, 2), 256, 0, stream>>>(qk, VT, Opart, ML);
  kComb<<<1024, 256, 0, stream>>>(Opart, ML, X);
  kProj<<<dim3(320, 2), 256, 0, stream>>>(X, WTp, bproj, (float*)d_out);
}

// Round 8
// 291.114 us; speedup vs baseline: 1.1539x; 1.0244x over previous
//
#include <hip/hip_runtime.h>
#include <hip/hip_bf16.h>

typedef unsigned short u16;
typedef unsigned int u32;
typedef __attribute__((ext_vector_type(8))) __bf16 bf16x8;
typedef __attribute__((ext_vector_type(4))) float f32x4;

#define INV_HD  0.03125f
#define INV_SHD 0.17677669529663687f
#define LOG2E   1.4426950408889634f

__device__ __forceinline__ float b2f(u16 u) {
  union { u32 i; float f; } v; v.i = ((u32)u) << 16; return v.f;
}
__device__ __forceinline__ u16 f2b(float f) {
  union { float f; u32 i; } v; v.f = f;
  u32 x = v.i;
  return (u16)((x + 0x7fffu + ((x >> 16) & 1u)) >> 16);
}
__device__ __forceinline__ bf16x8 ld16(const u16* p) {
  return *reinterpret_cast<const bf16x8*>(p);
}
union U8 { bf16x8 v; u16 s[8]; };
__device__ __forceinline__ bf16x8 cvt8(const float* p) {
  U8 u;
#pragma unroll
  for (int j = 0; j < 8; ++j) u.s[j] = f2b(p[j]);
  return u.v;
}
__device__ __forceinline__ u32 cvtpk(float a, float b) {
  u32 r;
  asm("v_cvt_pk_bf16_f32 %0, %1, %2" : "=v"(r) : "v"(a), "v"(b));
  return r;
}
// cross-half (lane ^ 32) reduce via builtin permlane32_swap (distinct regs guaranteed)
__device__ __forceinline__ float pl32max(float x) {
  union { float f; u32 u; } c; c.f = x;
  auto r = __builtin_amdgcn_permlane32_swap(c.u, c.u, false, false);
  union { u32 u; float f; } a, b; a.u = r[0]; b.u = r[1];
  return fmaxf(a.f, b.f);
}
__device__ __forceinline__ float pl32add(float x) {
  union { float f; u32 u; } c; c.f = x;
  auto r = __builtin_amdgcn_permlane32_swap(c.u, c.u, false, false);
  union { u32 u; float f; } a, b; a.u = r[0]; b.u = r[1];
  return a.f + b.f;
}

// ---------------- weight transpose + f32->bf16: WT[n][k] = W[k][n], K = 256 ----------------
__global__ void kT(const float* __restrict__ W, u16* __restrict__ WT, int N, int total)
{
  int i = blockIdx.x * 256 + threadIdx.x;
  if (i >= total) return;
  int n = i >> 8, k = i & 255;
  WT[i] = f2b(W[(size_t)k * N + n]);
}

// ---------------- pre-expand rel-pos bias into MFMA C-layout (swapped kSelf) ----------------
__global__ void kBias(const float* __restrict__ tblg, u16* __restrict__ BiasC)
{
  int gid = blockIdx.x * 256 + threadIdx.x;
  int lane = gid & 63, t = gid >> 6;     // t = h*16 + qt*4 + kt, in [0,128)
  int h = t >> 4, qt = (t >> 2) & 3, kt = t & 3;
  int lr = lane & 15, kg = lane >> 4;
  int q = qt * 16 + lr;
  int qi = q >> 3, qj = q & 7;
  ushort4 out;
#pragma unroll
  for (int i = 0; i < 4; ++i) {
    int key = kt * 16 + kg * 4 + i;
    int ki = key >> 3, kj = key & 7;
    int idx = (qi - ki + 7) * 15 + (qj - kj + 7);
    ((u16*)&out)[i] = f2b(tblg[idx * 8 + h] * (INV_SHD * LOG2E));
  }
  *reinterpret_cast<ushort4*>(BiasC + (size_t)(t * 64 + lane) * 4) = out;
}

// ---------------- QKV GEMM: [49152,256](f32) @ [256,768]
// Q columns are PRE-SCALED by INV_SHD*LOG2E (kSelf uses c0=INV_SHD, kCross uses Q directly).
__global__ __launch_bounds__(256) void kQKV(
    const float* __restrict__ xs1, const float* __restrict__ xs2, const float* __restrict__ xq,
    const u16* __restrict__ WT, const float* __restrict__ bias,
    u16* __restrict__ qk, u16* __restrict__ VT, u16* __restrict__ VST)
{
  __shared__ u16 vt[128 * 17];
  const int tid = threadIdx.x;
  const int lane = tid & 63, wid = tid >> 6;
  const int lr = lane & 15, kg = lane >> 4;
  const int m0 = blockIdx.x * 128 + wid * 32;
  const int n0 = blockIdx.y * 384;
  const int m0blk = blockIdx.x * 128;
  const int bb = m0blk / 6144, rloc = m0blk - bb * 6144;

  bf16x8 a[2][8];
#pragma unroll
  for (int mt = 0; mt < 2; ++mt) {
    int row = m0 + mt * 16 + lr;
    int b = row / 6144, r = row - b * 6144;
    const float* src;
    if (r < 4096)      src = xs1 + ((size_t)b * 4096 + r) * 256;
    else if (r < 5120) src = xs2 + ((size_t)b * 1024 + (r - 4096)) * 256;
    else               src = xq  + ((size_t)b * 1024 + (r - 5120)) * 256;
    src += kg * 8;
#pragma unroll
    for (int ks = 0; ks < 8; ++ks) a[mt][ks] = cvt8(src + ks * 32);
  }

  for (int nt = 0; nt < 24; ++nt) {
    const int n = n0 + nt * 16;
    const u16* bp = WT + (size_t)(n + lr) * 256 + kg * 8;
    f32x4 acc0 = {0.f,0.f,0.f,0.f}, acc1 = {0.f,0.f,0.f,0.f};
#pragma unroll
    for (int ks = 0; ks < 8; ++ks) {
      bf16x8 bq = ld16(bp + ks * 32);
      acc0 = __builtin_amdgcn_mfma_f32_16x16x32_bf16(a[0][ks], bq, acc0, 0, 0, 0);
      acc1 = __builtin_amdgcn_mfma_f32_16x16x32_bf16(a[1][ks], bq, acc1, 0, 0, 0);
    }
    float bv = bias[n + lr];
    if (n < 512) {
      const float qsc = (n < 256) ? (INV_SHD * LOG2E) : 1.f;
#pragma unroll
      for (int i = 0; i < 4; ++i) {
        int r0 = m0 + kg * 4 + i;
        qk[(size_t)r0 * 512 + n + lr]        = f2b((acc0[i] + bv) * qsc);
        qk[(size_t)(r0 + 16) * 512 + n + lr] = f2b((acc1[i] + bv) * qsc);
      }
    } else {
      const int mloc = wid * 32 + kg * 4;
#pragma unroll
      for (int i = 0; i < 4; ++i) {
        vt[(mloc + i) * 17 + lr]      = f2b(acc0[i] + bv);
        vt[(mloc + 16 + i) * 17 + lr] = f2b(acc1[i] + bv);
      }
      __syncthreads();
      {
        const int c = tid >> 4, kchunk = tid & 15;
        const int nc = n + c;
        const int hh = (nc - 512) >> 5, dd = (nc - 512) & 31;
        U8 pk;
#pragma unroll
        for (int j = 0; j < 8; ++j) pk.s[j] = vt[(kchunk * 8 + j) * 17 + c];
        u16* dst;
        if (rloc < 4096) {
          int y = (rloc >> 6) + (kchunk >> 3);
          int wkey = ((y >> 3) * 8 + (kchunk & 7)) * 64 + (y & 7) * 8;
          dst = VST + ((size_t)(bb * 8 + hh) * 32 + dd) * 4096 + wkey;
        } else {
          int key0 = (rloc < 5120) ? (rloc - 4096 + kchunk * 8)
                                   : (1024 + rloc - 5120 + kchunk * 8);
          dst = VT + ((size_t)(bb * 8 + hh) * 32 + dd) * 2048 + key0;
        }
        *reinterpret_cast<bf16x8*>(dst) = pk.v;
      }
      __syncthreads();
    }
  }
}

// ---------------- windowed self-attention, swapped QK^T (lane owns a q-row) ----------------
__global__ __launch_bounds__(256) void kSelf(
    const u16* __restrict__ qk, const u16* __restrict__ BiasC,
    const u16* __restrict__ VST, u16* __restrict__ X)
{
  __shared__ u16 Pl[4][64 * 72];
  const int tid = threadIdx.x;
  const int lane = tid & 63, wid = tid >> 6;
  const int lr = lane & 15, kg = lane >> 4;
  const int w = blockIdx.x >> 1;
  const int h = (blockIdx.x & 1) * 4 + wid;
  const int b = w >> 6, wz = w & 63;
  const int wy = wz >> 3, wx = wz & 7;
  const size_t tokbase = (size_t)b * 6144 + wy * 512 + wx * 8;
  const size_t xbase   = (size_t)b * 5120 + wy * 512 + wx * 8;
  u16* P = Pl[wid];

  bf16x8 qf[4], kf[4];
#pragma unroll
  for (int t4 = 0; t4 < 4; ++t4) {
    int t = t4 * 16 + lr;
    size_t row = tokbase + (t >> 3) * 64 + (t & 7);
    const u16* p = qk + row * 512 + h * 32 + kg * 8;
    qf[t4] = ld16(p);
    kf[t4] = ld16(p + 256);
  }
  bf16x8 vf[2][2];
#pragma unroll
  for (int dt = 0; dt < 2; ++dt)
#pragma unroll
    for (int ks = 0; ks < 2; ++ks)
      vf[dt][ks] = ld16(VST + ((size_t)(b * 8 + h) * 32 + dt * 16 + lr) * 4096
                        + wz * 64 + ks * 32 + kg * 8);
  f32x4 st[4][4];
#pragma unroll
  for (int qt = 0; qt < 4; ++qt)
#pragma unroll
    for (int kt = 0; kt < 4; ++kt) {
      f32x4 z = {0.f,0.f,0.f,0.f};
      st[qt][kt] = __builtin_amdgcn_mfma_f32_16x16x32_bf16(kf[kt], qf[qt], z, 0, 0, 0);
    }
  const float c0 = INV_SHD;   // Q pre-scaled by INV_SHD*LOG2E in kQKV
#pragma unroll
  for (int qt = 0; qt < 4; ++qt)
#pragma unroll
    for (int kt = 0; kt < 4; ++kt) {
      ushort4 bv = *reinterpret_cast<const ushort4*>(
          BiasC + (size_t)((h * 16 + qt * 4 + kt) * 64 + lane) * 4);
      st[qt][kt][0] = st[qt][kt][0] * c0 + b2f(bv.x);
      st[qt][kt][1] = st[qt][kt][1] * c0 + b2f(bv.y);
      st[qt][kt][2] = st[qt][kt][2] * c0 + b2f(bv.z);
      st[qt][kt][3] = st[qt][kt][3] * c0 + b2f(bv.w);
    }
  float l[4];
#pragma unroll
  for (int qt = 0; qt < 4; ++qt) {
    float mx = -1e30f;
#pragma unroll
    for (int kt = 0; kt < 4; ++kt)
      mx = fmaxf(mx, fmaxf(fmaxf(st[qt][kt][0], st[qt][kt][1]),
                           fmaxf(st[qt][kt][2], st[qt][kt][3])));
    mx = fmaxf(mx, __shfl_xor(mx, 16, 64));
    mx = pl32max(mx);
    float lsum = 0.f;
#pragma unroll
    for (int kt = 0; kt < 4; ++kt)
#pragma unroll
      for (int i = 0; i < 4; ++i) {
        float p = exp2f(st[qt][kt][i] - mx);
        st[qt][kt][i] = p; lsum += p;
      }
    lsum += __shfl_xor(lsum, 16, 64);
    lsum = pl32add(lsum);
    l[qt] = lsum;
  }
#pragma unroll
  for (int qt = 0; qt < 4; ++qt)
#pragma unroll
    for (int kt = 0; kt < 4; ++kt) {
      u32 w0 = cvtpk(st[qt][kt][0], st[qt][kt][1]);
      u32 w1 = cvtpk(st[qt][kt][2], st[qt][kt][3]);
      *reinterpret_cast<uint2*>(&P[(qt * 16 + lr) * 72 + kt * 16 + kg * 4]) = make_uint2(w0, w1);
    }
  f32x4 o[4][2] = {};
#pragma unroll
  for (int qt = 0; qt < 4; ++qt)
#pragma unroll
    for (int ks = 0; ks < 2; ++ks) {
      bf16x8 pf = ld16(P + (qt * 16 + lr) * 72 + ks * 32 + kg * 8);
      o[qt][0] = __builtin_amdgcn_mfma_f32_16x16x32_bf16(pf, vf[0][ks], o[qt][0], 0, 0, 0);
      o[qt][1] = __builtin_amdgcn_mfma_f32_16x16x32_bf16(pf, vf[1][ks], o[qt][1], 0, 0, 0);
    }
#pragma unroll
  for (int qt = 0; qt < 4; ++qt)
#pragma unroll
    for (int i = 0; i < 4; ++i) {
      float li = __shfl(l[qt], kg * 4 + i, 16);
      float inv = 1.f / li;
      int t = qt * 16 + kg * 4 + i;
      size_t xrow = xbase + (t >> 3) * 64 + (t & 7);
#pragma unroll
      for (int dt = 0; dt < 2; ++dt)
        X[xrow * 256 + h * 32 + dt * 16 + lr] = f2b(o[qt][dt][i] * inv);
    }
}

// ---------------- cross attention helpers ----------------
__device__ __forceinline__ void cload(
    const u16* __restrict__ kbase, const u16* __restrict__ vbase, int kc0, int lr, int kg,
    bf16x8 (&kf)[4], bf16x8 (&vf)[4])
{
#pragma unroll
  for (int kt = 0; kt < 4; ++kt)
    kf[kt] = ld16(kbase + (size_t)(kc0 + kt * 16 + lr) * 512);
#pragma unroll
  for (int ks = 0; ks < 2; ++ks) {
    vf[ks]     = ld16(vbase + (size_t)lr * 2048 + kc0 + ks * 32 + kg * 8);
    vf[2 + ks] = ld16(vbase + (size_t)(16 + lr) * 2048 + kc0 + ks * 32 + kg * 8);
  }
}

__device__ __forceinline__ void cstep(
    const bf16x8 (&kf)[4], const bf16x8 (&vf)[4], bf16x8 qf,
    u16* P, int lr, int kg, f32x4& o0, f32x4& o1, float& m, float& l)
{
  f32x4 st[4];
#pragma unroll
  for (int kt = 0; kt < 4; ++kt) {
    f32x4 z = {0.f,0.f,0.f,0.f};
    st[kt] = __builtin_amdgcn_mfma_f32_16x16x32_bf16(kf[kt], qf, z, 0, 0, 0);
  }
  float mx = fmaxf(fmaxf(fmaxf(st[0][0], st[0][1]), fmaxf(st[0][2], st[0][3])),
                   fmaxf(fmaxf(st[1][0], st[1][1]), fmaxf(st[1][2], st[1][3])));
  mx = fmaxf(mx, fmaxf(fmaxf(fmaxf(st[2][0], st[2][1]), fmaxf(st[2][2], st[2][3])),
                       fmaxf(fmaxf(st[3][0], st[3][1]), fmaxf(st[3][2], st[3][3]))));
  mx = fmaxf(mx, __shfl_xor(mx, 16, 64));
  mx = pl32max(mx);
  if (__all(mx <= m + 8.f)) {
    float lsum = 0.f;
#pragma unroll
    for (int kt = 0; kt < 4; ++kt)
#pragma unroll
      for (int i = 0; i < 4; ++i) {
        float p = exp2f(st[kt][i] - m); st[kt][i] = p; lsum += p;
      }
    lsum += __shfl_xor(lsum, 16, 64);
    l += pl32add(lsum);
  } else {
    float mn = fmaxf(m, mx);
    float sca = exp2f(m - mn);
    float lsum = 0.f;
#pragma unroll
    for (int kt = 0; kt < 4; ++kt)
#pragma unroll
      for (int i = 0; i < 4; ++i) {
        float p = exp2f(st[kt][i] - mn); st[kt][i] = p; lsum += p;
      }
    lsum += __shfl_xor(lsum, 16, 64);
    l = l * sca + pl32add(lsum);
    m = mn;
#pragma unroll
    for (int i = 0; i < 4; ++i) {
      float si = __shfl(sca, kg * 4 + i, 16);
      o0[i] *= si; o1[i] *= si;
    }
  }
#pragma unroll
  for (int kt = 0; kt < 4; ++kt) {
    u32 w0 = cvtpk(st[kt][0], st[kt][1]);
    u32 w1 = cvtpk(st[kt][2], st[kt][3]);
    *reinterpret_cast<uint2*>(&P[lr * 72 + kt * 16 + kg * 4]) = make_uint2(w0, w1);
  }
#pragma unroll
  for (int ks = 0; ks < 2; ++ks) {
    bf16x8 pf = ld16(P + lr * 72 + ks * 32 + kg * 8);
    o0 = __builtin_amdgcn_mfma_f32_16x16x32_bf16(pf, vf[ks],     o0, 0, 0, 0);
    o1 = __builtin_amdgcn_mfma_f32_16x16x32_bf16(pf, vf[2 + ks], o1, 0, 0, 0);
  }
}

// ---------------- cross attention: 2 q-tiles/wave share K/V, KV-split=2 ----------------
__global__ __launch_bounds__(256, 4) void kCross(
    const u16* __restrict__ qk, const u16* __restrict__ VT,
    u16* __restrict__ Opart, float* __restrict__ ML)
{
  __shared__ u16 Pl[4][2][16 * 72];
  const int tid = threadIdx.x;
  const int lane = tid & 63, wid = tid >> 6;
  const int lr = lane & 15, kg = lane >> 4;
  const int bh = blockIdx.x, b = bh >> 3, h = bh & 7;
  const int s = blockIdx.z;
  const int q0 = blockIdx.y * 128 + wid * 16;     // tile A; tile B = q0 + 64
  const size_t qrow0 = (size_t)b * 6144 + 5120;
  const size_t krow0 = (size_t)b * 6144 + 4096;
  const u16* kbase = qk + ((s ? qrow0 : krow0) * 512) + 256 + h * 32 + kg * 8;
  const u16* vbase = VT + (size_t)bh * 32 * 2048 + s * 1024;
  u16* PA = Pl[wid][0];
  u16* PB = Pl[wid][1];

  bf16x8 qfA = ld16(qk + (qrow0 + q0      + lr) * 512 + h * 32 + kg * 8);
  bf16x8 qfB = ld16(qk + (qrow0 + q0 + 64 + lr) * 512 + h * 32 + kg * 8);

  f32x4 oA0 = {0.f,0.f,0.f,0.f}, oA1 = {0.f,0.f,0.f,0.f};
  f32x4 oB0 = {0.f,0.f,0.f,0.f}, oB1 = {0.f,0.f,0.f,0.f};
  float mA = -1e30f, lA = 0.f, mB = -1e30f, lB = 0.f;

  bf16x8 kA[4], vA[4], kB[4], vB[4];
  cload(kbase, vbase, 0, lr, kg, kA, vA);
#pragma unroll 1
  for (int ck2 = 0; ck2 < 8; ++ck2) {
    const int kc = ck2 * 128;
    cload(kbase, vbase, (kc + 64) & 1023, lr, kg, kB, vB);   // prefetch next tile
    cstep(kA, vA, qfA, PA, lr, kg, oA0, oA1, mA, lA);
    cstep(kA, vA, qfB, PB, lr, kg, oB0, oB1, mB, lB);
    cload(kbase, vbase, (kc + 128) & 1023, lr, kg, kA, vA);
    cstep(kB, vB, qfA, PA, lr, kg, oA0, oA1, mA, lA);
    cstep(kB, vB, qfB, PB, lr, kg, oB0, oB1, mB, lB);
  }

  const size_t rowb = (size_t)(s * 64 + bh) * 1024;
#pragma unroll
  for (int i = 0; i < 4; ++i) {
    int qa = q0 + kg * 4 + i, qb = qa + 64;
    Opart[(rowb + qa) * 32 + lr]      = f2b(oA0[i]);
    Opart[(rowb + qa) * 32 + 16 + lr] = f2b(oA1[i]);
    Opart[(rowb + qb) * 32 + lr]      = f2b(oB0[i]);
    Opart[(rowb + qb) * 32 + 16 + lr] = f2b(oB1[i]);
  }
  if (kg == 0) {
    *reinterpret_cast<float2*>(ML + (rowb + q0 + lr) * 2)      = make_float2(mA, lA);
    *reinterpret_cast<float2*>(ML + (rowb + q0 + 64 + lr) * 2) = make_float2(mB, lB);
  }
}

// ---------------- combine the 2 KV-splits ----------------
__global__ __launch_bounds__(256) void kComb(
    const u16* __restrict__ Opart, const float* __restrict__ ML, u16* __restrict__ X)
{
  int gid = blockIdx.x * 256 + threadIdx.x;   // 262144
  int row = gid >> 2;                         // bh*1024 + q
  int dp = (gid & 3) * 8;
  int bh = row >> 10, q = row & 1023;
  int b = bh >> 3, h = bh & 7;
  float2 ml0 = *reinterpret_cast<const float2*>(ML + (size_t)row * 2);
  float2 ml1 = *reinterpret_cast<const float2*>(ML + (size_t)(65536 + row) * 2);
  float ms = fmaxf(ml0.x, ml1.x);
  float f0 = exp2f(ml0.x - ms), f1 = exp2f(ml1.x - ms);
  float inv = 1.f / (ml0.y * f0 + ml1.y * f1);
  f0 *= inv; f1 *= inv;
  U8 a, c, r;
  a.v = ld16(Opart + (size_t)row * 32 + dp);
  c.v = ld16(Opart + ((size_t)(65536 + row) * 32 + dp));
#pragma unroll
  for (int j = 0; j < 8; ++j) r.s[j] = f2b(b2f(a.s[j]) * f0 + b2f(c.s[j]) * f1);
  size_t xrow = (size_t)b * 5120 + 4096 + q;
  *reinterpret_cast<bf16x8*>(X + xrow * 256 + h * 32 + dp) = r.v;
}

// ---------------- output projection: [40960,256] @ [256,256] -> f32 out ----------------
__global__ __launch_bounds__(256) void kProj(
    const u16* __restrict__ Xin, const u16* __restrict__ WT, const float* __restrict__ bias,
    float* __restrict__ out)
{
  const int tid = threadIdx.x;
  const int lane = tid & 63, wid = tid >> 6;
  const int lr = lane & 15, kg = lane >> 4;
  const int m0 = blockIdx.x * 128 + wid * 32;
  const int n0 = blockIdx.y * 128;
  bf16x8 a[2][8];
#pragma unroll
  for (int mt = 0; mt < 2; ++mt) {
    const u16* src = Xin + (size_t)(m0 + mt * 16 + lr) * 256 + kg * 8;
#pragma unroll
    for (int ks = 0; ks < 8; ++ks) a[mt][ks] = ld16(src + ks * 32);
  }
  for (int nt = 0; nt < 8; ++nt) {
    const int n = n0 + nt * 16;
    const u16* bp = WT + (size_t)(n + lr) * 256 + kg * 8;
    f32x4 acc0 = {0.f,0.f,0.f,0.f}, acc1 = {0.f,0.f,0.f,0.f};
#pragma unroll
    for (int ks = 0; ks < 8; ++ks) {
      bf16x8 bq = ld16(bp + ks * 32);
      acc0 = __builtin_amdgcn_mfma_f32_16x16x32_bf16(a[0][ks], bq, acc0, 0, 0, 0);
      acc1 = __builtin_amdgcn_mfma_f32_16x16x32_bf16(a[1][ks], bq, acc1, 0, 0, 0);
    }
    float bv = bias[n + lr];
#pragma unroll
    for (int i = 0; i < 4; ++i) {
      int r0 = m0 + kg * 4 + i;
      out[(size_t)r0 * 256 + n + lr]        = acc0[i] + bv;
      out[(size_t)(r0 + 16) * 256 + n + lr] = acc1[i] + bv;
    }
  }
}

extern "C" void kernel_launch(void* const* d_in, const int* in_sizes, int n_in,
                              void* d_out, int out_size, void* d_ws, size_t ws_size,
                              hipStream_t stream)
{
  const float* xs1   = (const float*)d_in[0];
  const float* xs2   = (const float*)d_in[1];
  const float* xq    = (const float*)d_in[2];
  const float* Wqkv  = (const float*)d_in[3];
  const float* bqkv  = (const float*)d_in[4];
  const float* Wproj = (const float*)d_in[5];
  const float* bproj = (const float*)d_in[6];
  const float* tbl   = (const float*)d_in[7];

  u16* ws  = (u16*)d_ws;
  u16* qk  = ws;                 // 49152*512 = 25165824 elems (bf16)
  u16* X   = qk + 25165824;      // 40960*256 = 10485760
  u16* WTq = X + 10485760;       // 768*256   =   196608
  u16* WTp = WTq + 196608;       // 256*256   =    65536
  u16* VT  = WTp + 65536;        // 8*8*32*2048 = 4194304
  u16* VST = VT + 4194304;       // 8*8*32*4096 = 8388608

  // scratch inside d_out (fully overwritten by kProj at the end):
  u16*   BiasC = (u16*)d_out;                               // 131072 u16  (256 KB)
  float* ML    = (float*)((char*)d_out + 262144);           // 262144 f32  (1 MB)
  u16*   Opart = (u16*)((char*)d_out + 1310720);            // 4194304 u16 (8 MB)

  kT<<<768, 256, 0, stream>>>(Wqkv, WTq, 768, 196608);
  kT<<<256, 256, 0, stream>>>(Wproj, WTp, 256, 65536);
  kBias<<<32, 256, 0, stream>>>(tbl, BiasC);
  kQKV<<<dim3(384, 2), 256, 0, stream>>>(xs1, xs2, xq, WTq, bqkv, qk, VT, VST);
  kSelf<<<1024, 256, 0, stream>>>(qk, BiasC, VST, X);
  kCross<<<dim3(64, 8, 2), 256, 0, stream>>>(qk, VT, Opart, ML);
  kComb<<<1024, 256, 0, stream>>>(Opart, ML, X);
  kProj<<<dim3(320, 2), 256, 0, stream>>>(X, WTp, bproj, (float*)d_out);
}